// Round 4
// baseline (307.888 us; speedup 1.0000x reference)
//
#include <hip/hip_runtime.h>
#include <cfloat>
#include <cstdint>

// Problem constants (reference: B=32, C=256, H=W=64, nh=4, hid=C/4=64, S=40)
#define B_    32
#define C_    256
#define HW_   4096
#define NH_   4
#define HID_  64
#define SSEL_ 40
#define GADD_ 0.0075f   // 0.3 * (1/40): pixel_imp collapses to 1/S exactly

using half8_t = __attribute__((ext_vector_type(8))) _Float16;
using half4_t = __attribute__((ext_vector_type(4))) _Float16;
using f32x4_t = __attribute__((ext_vector_type(4))) float;

// ---------------------------------------------------------------------------
// K1 v6: fp16 MFMA MLP, B-operand loaded GLOBAL->REG (no X LDS staging).
// v5 post-mortem: fused epilogue at 2 blocks/CU (69KB LDS) streamed at
// 2.1 TB/s (latency-bound at 8 waves/CU) — fusion reverted. v3-vs-v4
// neutrality proved scalar B-loads are fine, so XTu is deleted outright:
//   LDS = WHu only (32 KB)  ->  4 blocks/CU, grid 1024 = 16 waves/CU,
//   ONE barrier total (after W1 convert), no per-chunk vmcnt(0) drains.
// Block: 256 thr / 4 waves, px-tile 128 (wave wv owns 32 px, nt=0..1).
// B-frag: 8 k-consecutive scalar loads per (nt): wave instr = 64 lanes x 4B
// in 4x64B segments, every byte consumed. sum|x| folds into the same loads;
// per-lane partial covers ch {ck*64+k2*32+g*8+e} -> shfl_xor(16,32) over the
// 4 g-lanes completes 256 ch per px (same tree as the layer-2 epilogue).
// ---------------------------------------------------------------------------
__global__ __launch_bounds__(256, 4) void k_mlp(
    const float* __restrict__ x,
    const float* __restrict__ w1, const float* __restrict__ b1,
    const float* __restrict__ w2, const float* __restrict__ b2,
    float* __restrict__ m, float* __restrict__ imp)
{
    __shared__ __align__(16) uint32_t WHu[64 * 128];   // fp16-pair W1 [hid][ch/2] 32KB

    const int t    = threadIdx.x;
    const int b    = blockIdx.x >> 5;            // 32 px-tiles per batch
    const int p0   = (blockIdx.x & 31) << 7;     // 128-px tile base
    const int lane = t & 63;
    const int wv   = t >> 6;                     // wave id: 32-px slice
    const int g    = lane >> 4;                  // k-group / D-row group
    const int lr   = lane & 15;                  // A-row / B-col / D-col

    // ---- stage W1 -> fp16 LDS once (coalesced float4 reads of 64 KB) ----
    #pragma unroll
    for (int i = 0; i < 16; ++i) {
        const int q   = t + (i << 8);            // float4 index in w1
        const int hid = q >> 6;
        const float4 wq = *(const float4*)(w1 + ((size_t)q << 2));
        half4_t hv;
        hv[0] = (_Float16)wq.x; hv[1] = (_Float16)wq.y;
        hv[2] = (_Float16)wq.z; hv[3] = (_Float16)wq.w;
        const int col = ((q & 63) * 2) ^ ((hid & 7) << 2);
        *reinterpret_cast<half4_t*>(&WHu[hid * 128 + col]) = hv;
    }

    // ---- accumulators seeded with b1 (C-in of first MFMA) ----
    f32x4_t acc[4][2];
    #pragma unroll
    for (int mt = 0; mt < 4; ++mt) {
        const float4 bv = *(const float4*)(b1 + mt * 16 + g * 4);
        #pragma unroll
        for (int nt = 0; nt < 2; ++nt) {
            acc[mt][nt][0] = bv.x; acc[mt][nt][1] = bv.y;
            acc[mt][nt][2] = bv.z; acc[mt][nt][3] = bv.w;
        }
    }
    __syncthreads();                              // WHu ready (only barrier)

    float sa[2] = {0.f, 0.f};                     // |x| partials per nt (this px)
    // lane's px column base: px = wv*32 + nt*16 + lr; lane's ch base: g*8
    const float* __restrict__ xp =
        x + ((size_t)b << 20) + (size_t)(g * 8) * HW_ + p0 + wv * 32 + lr;

    for (int ck = 0; ck < 4; ++ck) {
        #pragma unroll
        for (int k2 = 0; k2 < 2; ++k2) {
            const int ks = ck * 2 + k2;
            // ---- B-frags straight from global (ch = ck*64+k2*32+g*8+e) ----
            half8_t bf[2];
            #pragma unroll
            for (int nt = 0; nt < 2; ++nt) {
                const float* __restrict__ xc =
                    xp + (size_t)(ck * 64 + k2 * 32) * HW_ + nt * 16;
                float v[8];
                #pragma unroll
                for (int e = 0; e < 8; ++e) v[e] = xc[(size_t)e * HW_];
                #pragma unroll
                for (int e = 0; e < 8; ++e) {
                    bf[nt][e] = (_Float16)v[e];
                    sa[nt] += fabsf(v[e]);
                }
            }
            // ---- A-frags from LDS: W1[16mt+lr][32ks+8g..+7] ----
            half8_t af[4];
            #pragma unroll
            for (int mt = 0; mt < 4; ++mt) {
                const int hid = mt * 16 + lr;
                const int col = (ks * 16 + g * 4) ^ ((hid & 7) << 2);
                af[mt] = *reinterpret_cast<const half8_t*>(&WHu[hid * 128 + col]);
            }
            #pragma unroll
            for (int mt = 0; mt < 4; ++mt)
                #pragma unroll
                for (int nt = 0; nt < 2; ++nt)
                    acc[mt][nt] = __builtin_amdgcn_mfma_f32_16x16x32_f16(
                        af[mt], bf[nt], acc[mt][nt], 0, 0, 0);
        }
    }

    // ---- importance: complete 256-ch sum per px across the 4 g-lanes ----
    #pragma unroll
    for (int nt = 0; nt < 2; ++nt) {
        float s = sa[nt];
        s += __shfl_xor(s, 16, 64);
        s += __shfl_xor(s, 32, 64);
        if (g == 0)
            imp[((size_t)b << 12) + p0 + wv * 32 + nt * 16 + lr] = s;
    }

    // ---- layer 2 (64 -> 4 heads) + sigmoid, fully in-register ----
    // lane holds relu(H1[hid][px]) for hid = 16mt + 4g + r, px = 32wv+16nt+lr
    float4 w2r[4][4];
    #pragma unroll
    for (int hd = 0; hd < 4; ++hd)
        #pragma unroll
        for (int mt = 0; mt < 4; ++mt)
            w2r[hd][mt] = *(const float4*)(w2 + hd * 64 + mt * 16 + g * 4);

    #pragma unroll
    for (int nt = 0; nt < 2; ++nt) {
        float s[4] = {0.f, 0.f, 0.f, 0.f};
        #pragma unroll
        for (int mt = 0; mt < 4; ++mt) {
            const float h0 = fmaxf(acc[mt][nt][0], 0.f);
            const float h1 = fmaxf(acc[mt][nt][1], 0.f);
            const float h2 = fmaxf(acc[mt][nt][2], 0.f);
            const float h3 = fmaxf(acc[mt][nt][3], 0.f);
            #pragma unroll
            for (int hd = 0; hd < 4; ++hd) {
                s[hd] = fmaf(w2r[hd][mt].x, h0, s[hd]);
                s[hd] = fmaf(w2r[hd][mt].y, h1, s[hd]);
                s[hd] = fmaf(w2r[hd][mt].z, h2, s[hd]);
                s[hd] = fmaf(w2r[hd][mt].w, h3, s[hd]);
            }
        }
        #pragma unroll
        for (int hd = 0; hd < 4; ++hd) {          // combine the 4 g-lanes
            s[hd] += __shfl_xor(s[hd], 16, 64);
            s[hd] += __shfl_xor(s[hd], 32, 64);
        }
        if (g == 0) {
            const float ssum =
                  1.f / (1.f + __expf(-(s[0] + b2[0])))
                + 1.f / (1.f + __expf(-(s[1] + b2[1])))
                + 1.f / (1.f + __expf(-(s[2] + b2[2])))
                + 1.f / (1.f + __expf(-(s[3] + b2[3])));
            m[((size_t)b << 12) + p0 + wv * 32 + nt * 16 + lr] = 0.175f * ssum;
        }
    }
}

// ---------------------------------------------------------------------------
// K2: per-batch top-40 extraction; winners get m += 0.3/40. (v4 version)
// ---------------------------------------------------------------------------
__global__ __launch_bounds__(64) void k_topk(
    const float* __restrict__ imp, float* __restrict__ m)
{
    const int b    = blockIdx.x;
    const int lane = threadIdx.x;
    const float* __restrict__ ib = imp + (size_t)b * HW_;
    float* __restrict__ mb = m + (size_t)b * HW_;

    float v[64];
    #pragma unroll
    for (int i = 0; i < 64; ++i) v[i] = ib[i * 64 + lane];

    float g[8];
    #pragma unroll
    for (int k = 0; k < 8; ++k) {
        float gm = v[8 * k];
        #pragma unroll
        for (int i = 1; i < 8; ++i) gm = fmaxf(gm, v[8 * k + i]);
        g[k] = gm;
    }

    for (int it = 0; it < SSEL_; ++it) {
        float lm = g[0];
        #pragma unroll
        for (int k = 1; k < 8; ++k) lm = fmaxf(lm, g[k]);
        float wm = lm;
        #pragma unroll
        for (int off = 32; off >= 1; off >>= 1)
            wm = fmaxf(wm, __shfl_xor(wm, off, 64));
        #pragma unroll
        for (int k = 0; k < 8; ++k) {
            if (__any(g[k] == wm)) {
                int gi = -1;
                #pragma unroll
                for (int i = 0; i < 8; ++i) {
                    if (v[8 * k + i] == wm) {
                        gi = (8 * k + i) * 64 + lane;
                        v[8 * k + i] = -FLT_MAX;
                    }
                }
                float gm = v[8 * k];
                #pragma unroll
                for (int i = 1; i < 8; ++i) gm = fmaxf(gm, v[8 * k + i]);
                g[k] = gm;
                if (gi >= 0) mb[gi] += GADD_;
            }
        }
    }
}

// ---------------------------------------------------------------------------
// K3: out[b,c,p] = x[b,c,p] * m[b,p]   (float4; m plane L2/L3-resident)
// High-occupancy streaming kernel — this is the right home for the 256 MiB
// stream (v5 lesson: fusing it into the 2-blocks/CU GEMM ran at 2.1 TB/s).
// ---------------------------------------------------------------------------
__global__ __launch_bounds__(256) void k_apply(
    const float4* __restrict__ x4, const float* __restrict__ m,
    float4* __restrict__ o4)
{
    const size_t i = (size_t)blockIdx.x * 256 + threadIdx.x;
    const size_t flat = i << 2;
    const int b = (int)(flat >> 20);          // C_*HW_ = 2^20
    const int p = (int)(flat & (HW_ - 1));
    const float4 mv = *(const float4*)(m + ((size_t)b << 12) + p);
    const float4 xv = x4[i];
    float4 r;
    r.x = xv.x * mv.x; r.y = xv.y * mv.y;
    r.z = xv.z * mv.z; r.w = xv.w * mv.w;
    o4[i] = r;
}

extern "C" void kernel_launch(void* const* d_in, const int* in_sizes, int n_in,
                              void* d_out, int out_size, void* d_ws, size_t ws_size,
                              hipStream_t stream)
{
    const float* x  = (const float*)d_in[0];
    const float* w1 = (const float*)d_in[1];  // gm_w1 [64,256]
    const float* b1 = (const float*)d_in[2];  // gm_b1 [64]
    const float* w2 = (const float*)d_in[3];  // gm_w2 [4,64]
    const float* b2 = (const float*)d_in[4];  // gm_b2 [4]
    // d_in[5..9] (qkv_w, ge_*) provably do not affect the output: softmax rows
    // mean to 1/S regardless of scores, so pixel_imp == 1/40 exactly.

    float* m   = (float*)d_ws;                 // B*HW floats (512 KB)
    float* imp = m + (size_t)B_ * HW_;         // B*HW floats (512 KB)
    float* out = (float*)d_out;

    k_mlp<<<dim3(B_ * (HW_ / 128)), dim3(256), 0, stream>>>(x, w1, b1, w2, b2, m, imp);
    k_topk<<<dim3(B_), dim3(64), 0, stream>>>(imp, m);
    const int n4 = (B_ * C_ * HW_) / 4;
    k_apply<<<dim3(n4 / 256), dim3(256), 0, stream>>>((const float4*)x, m, (float4*)out);
}